// Round 6
// baseline (154.306 us; speedup 1.0000x reference)
//
#include <hip/hip_runtime.h>

// 3-level inverse Haar DWT, fully fused, one pass.
// Input  h  : (16, 192, 64, 64) f32   -> 50.3 MB
// Output out: (16, 3, 512, 512) f32   -> 50.3 MB
//
// Haar synthesis per level:
//   out(2i,2j)  =.5(ll+lh+hl+hh)   out(2i,2j+1)  =.5(ll+lh-hl-hh)
//   out(2i+1,2j)=.5(ll-lh+hl-hh)   out(2i+1,2j+1)=.5(ll-lh-hl+hh)
//
// Each thread: 2x16 output patch (rows 2*i0, 2*i0+1; cols 16*js .. 16*js+15).
//   yh0 (j0 = 8js..8js+7) : 2 float4 per subband, 6 loads (unique per thread)
//   yh1 (j1 = 4js..4js+3) : 1 float4 per subband, 3 loads (shared x2 rows in-block)
//   yh2+LL (j2=2js,2js+1) : float2, 4 loads            (shared x4 rows in-block)
// 13 loads / 176 B in flight per thread; 8 float4 NT stores.

typedef float f32x4 __attribute__((ext_vector_type(4)));

__global__ __launch_bounds__(256) void wave_decoder_kernel(
    const float* __restrict__ h, float* __restrict__ out) {
    const int tid = threadIdx.x;
    const int sp  = blockIdx.x * 256 + tid;   // [0, 8192) per (n,c) image
    const int js  = sp & 31;                  // 16-col group [0,32)
    const int i0  = sp >> 5;                  // level-0 row [0,256)
    const int nc  = blockIdx.y;               // n*3 + c
    const int c   = nc % 3;
    const float* __restrict__ hb = h + (size_t)(nc / 3) * (192 * 4096);

    const int i1 = i0 >> 1;                   // [0,128)
    const int i2 = i0 >> 2;                   // [0,64)

    // ---- issue all loads up front (independent) ----
    // level 2 (ch 183+3c+b) + LL (ch c): j2 = 2js, 2js+1
    const int s2 = i2 * 64 + (js << 1);
    const float2 llv = *(const float2*)(hb + c * 4096 + s2);
    const float* __restrict__ y2 = hb + (183 + 3 * c) * 4096 + s2;
    const float2 lh2 = *(const float2*)(y2);
    const float2 hl2 = *(const float2*)(y2 + 4096);
    const float2 hh2 = *(const float2*)(y2 + 2 * 4096);

    // level 1 (ch 147+12c+4b+2*ph+pw): j1 = 4js..4js+3
    const int s1 = (i1 & 63) * 64 + ((js << 2) & 63);
    const float* __restrict__ y1 =
        hb + (147 + 12 * c + (i1 >> 6) * 2 + (js >> 4)) * 4096 + s1;
    const f32x4 lh1 = *(const f32x4*)(y1);
    const f32x4 hl1 = *(const f32x4*)(y1 + 4 * 4096);
    const f32x4 hh1 = *(const f32x4*)(y1 + 8 * 4096);

    // level 0 (ch 3+48c+16b+4*ph+pw): j0 = 8js..8js+7 (never crosses pw boundary)
    const int s0 = (i0 & 63) * 64 + ((js << 3) & 63);
    const float* __restrict__ y0 =
        hb + (3 + 48 * c + (i0 >> 6) * 4 + (js >> 3)) * 4096 + s0;
    const f32x4 lh0a = *(const f32x4*)(y0);
    const f32x4 lh0b = *(const f32x4*)(y0 + 4);
    const f32x4 hl0a = *(const f32x4*)(y0 + 16 * 4096);
    const f32x4 hl0b = *(const f32x4*)(y0 + 16 * 4096 + 4);
    const f32x4 hh0a = *(const f32x4*)(y0 + 32 * 4096);
    const f32x4 hh0b = *(const f32x4*)(y0 + 32 * 4096 + 4);

    // ---- level 2 synthesis: ll2[k] for j1 = 4js+k ----
    const float sx2 = (i1 & 1) ? -1.f : 1.f;
    float ll2[4];
    {
        const float ax = llv.x + sx2 * lh2.x, bx = hl2.x + sx2 * hh2.x;
        ll2[0] = 0.5f * (ax + bx);  ll2[1] = 0.5f * (ax - bx);
        const float ay = llv.y + sx2 * lh2.y, by = hl2.y + sx2 * hh2.y;
        ll2[2] = 0.5f * (ay + by);  ll2[3] = 0.5f * (ay - by);
    }

    // ---- level 1 synthesis: ll1[m] for j0 = 8js+m ----
    const float sx1 = (i0 & 1) ? -1.f : 1.f;
    float ll1[8];
#pragma unroll
    for (int k = 0; k < 4; ++k) {
        const float t = ll2[k] + sx1 * lh1[k];
        const float u = hl1[k] + sx1 * hh1[k];
        ll1[2 * k]     = 0.5f * (t + u);
        ll1[2 * k + 1] = 0.5f * (t - u);
    }

    // ---- level 0 synthesis -> 2 rows x 16 cols (registers; fully unrolled) ----
    float lh0[8], hl0[8], hh0[8];
#pragma unroll
    for (int k = 0; k < 4; ++k) {
        lh0[k] = lh0a[k];  lh0[k + 4] = lh0b[k];
        hl0[k] = hl0a[k];  hl0[k + 4] = hl0b[k];
        hh0[k] = hh0a[k];  hh0[k + 4] = hh0b[k];
    }
    float r0[16], r1[16];
#pragma unroll
    for (int k = 0; k < 8; ++k) {
        const float p  = ll1[k] + lh0[k], q  = hl0[k] + hh0[k];
        const float pm = ll1[k] - lh0[k], qm = hl0[k] - hh0[k];
        r0[2 * k]     = 0.5f * (p + q);
        r0[2 * k + 1] = 0.5f * (p - q);
        r1[2 * k]     = 0.5f * (pm + qm);
        r1[2 * k + 1] = 0.5f * (pm - qm);
    }

    float* __restrict__ ob =
        out + ((size_t)nc * 512 + (i0 << 1)) * 512 + (js << 4);
#pragma unroll
    for (int v = 0; v < 4; ++v) {
        f32x4 s0v, s1v;
#pragma unroll
        for (int e = 0; e < 4; ++e) { s0v[e] = r0[4 * v + e]; s1v[e] = r1[4 * v + e]; }
        __builtin_nontemporal_store(s0v, (f32x4*)(ob + 4 * v));
        __builtin_nontemporal_store(s1v, (f32x4*)(ob + 512 + 4 * v));
    }
}

extern "C" void kernel_launch(void* const* d_in, const int* in_sizes, int n_in,
                              void* d_out, int out_size, void* d_ws, size_t ws_size,
                              hipStream_t stream) {
    const float* h = (const float*)d_in[0];
    float* out = (float*)d_out;
    dim3 grid(32, 48);           // 32 spatial blocks x (n*3+c)
    wave_decoder_kernel<<<grid, dim3(256, 1, 1), 0, stream>>>(h, out);
}

// Round 7
// 97.346 us; speedup vs baseline: 1.5851x; 1.5851x over previous
//
#include <hip/hip_runtime.h>

// 3-level inverse Haar DWT, fully fused, one pass.
// Input  h  : (16, 192, 64, 64) f32   -> 50.3 MB
// Output out: (16, 3, 512, 512) f32   -> 50.3 MB
//
// Layout: ONE WAVE per output row-pair (rows 2*i0, 2*i0+1). Lane u covers
// output cols {4u..4u+3} (group A) and {256+4u..256+4u+3} (group B).
// => every load is lane-contiguous, and all 4 NT float4 stores per lane are
// FULLY contiguous across the wave (1024B per instruction, whole cache lines;
// R6's 64B-stride partial-line NT stores caused 2.55x write amplification).
//
// Haar synthesis per 2x2 block:
//   out(2i,2j)  =.5(ll+lh+hl+hh)   out(2i,2j+1)  =.5(ll+lh-hl-hh)
//   out(2i+1,2j)=.5(ll-lh+hl-hh)   out(2i+1,2j+1)=.5(ll-lh-hl+hh)

typedef float f32x4 __attribute__((ext_vector_type(4)));

__global__ __launch_bounds__(256) void wave_decoder_kernel(
    const float* __restrict__ h, float* __restrict__ out) {
    const int tid = threadIdx.x;
    const int u   = tid & 63;                  // lane
    const int i0  = (blockIdx.x << 2) + (tid >> 6);   // level-0 row [0,256)
    const int nc  = blockIdx.y;                // n*3 + c
    const int c   = nc % 3;
    const float* __restrict__ hb = h + (size_t)(nc / 3) * (192 * 4096);
    const int i1 = i0 >> 1, i2 = i0 >> 2;

    // ---- loads (all lane-contiguous) ----
    // level 2 + LL: j2 = u>>1 (A), 32+(u>>1) (B)
    const int s2 = i2 * 64 + (u >> 1);
    const float llA  = hb[c * 4096 + s2];
    const float llB  = hb[c * 4096 + s2 + 32];
    const float* __restrict__ y2 = hb + (183 + 3 * c) * 4096 + s2;
    const float lh2A = y2[0],          lh2B = y2[32];
    const float hl2A = y2[4096],       hl2B = y2[4096 + 32];
    const float hh2A = y2[2 * 4096],   hh2B = y2[2 * 4096 + 32];

    // level 1: j1 = u (A, pw=0), 64+u (B, pw=1)
    const float* __restrict__ y1 =
        hb + (147 + 12 * c + (i1 >> 6) * 2) * 4096 + (i1 & 63) * 64 + u;
    const float lh1A = y1[0],          lh1B = y1[4096];
    const float hl1A = y1[4 * 4096],   hl1B = y1[5 * 4096];
    const float hh1A = y1[8 * 4096],   hh1B = y1[9 * 4096];

    // level 0: j0 = {2u,2u+1} (A, pw=u>>5), {128+2u,128+2u+1} (B, pw=2+(u>>5))
    const float* __restrict__ y0 =
        hb + (3 + 48 * c + (i0 >> 6) * 4 + (u >> 5)) * 4096
           + (i0 & 63) * 64 + ((u << 1) & 63);
    const float2 lh0A = *(const float2*)(y0);
    const float2 hl0A = *(const float2*)(y0 + 16 * 4096);
    const float2 hh0A = *(const float2*)(y0 + 32 * 4096);
    const float2 lh0B = *(const float2*)(y0 + 2 * 4096);
    const float2 hl0B = *(const float2*)(y0 + 18 * 4096);
    const float2 hh0B = *(const float2*)(y0 + 34 * 4096);

    // ---- level-2 synthesis: ll_lvl1(i1, j1) ----
    const float sx2 = (i1 & 1) ? -1.f : 1.f;
    const float sy2 = (u & 1) ? -1.f : 1.f;
    const float ll2A = 0.5f * ((llA + sx2 * lh2A) + sy2 * (hl2A + sx2 * hh2A));
    const float ll2B = 0.5f * ((llB + sx2 * lh2B) + sy2 * (hl2B + sx2 * hh2B));

    // ---- level-1 synthesis: ll_lvl0(i0, 2u / 2u+1) and (i0, 128+2u / +1) ----
    const float sx1 = (i0 & 1) ? -1.f : 1.f;
    const float tA = ll2A + sx1 * lh1A, vA = hl1A + sx1 * hh1A;
    const float ll1A0 = 0.5f * (tA + vA), ll1A1 = 0.5f * (tA - vA);
    const float tB = ll2B + sx1 * lh1B, vB = hl1B + sx1 * hh1B;
    const float ll1B0 = 0.5f * (tB + vB), ll1B1 = 0.5f * (tB - vB);

    // ---- level-0 synthesis -> 2 rows x (4 + 4) cols ----
    f32x4 r0A, r0B, r1A, r1B;
    {
        const float p = ll1A0 + lh0A.x, q = hl0A.x + hh0A.x;
        r0A[0] = 0.5f * (p + q);  r0A[1] = 0.5f * (p - q);
        const float pm = ll1A0 - lh0A.x, qm = hl0A.x - hh0A.x;
        r1A[0] = 0.5f * (pm + qm); r1A[1] = 0.5f * (pm - qm);
    }
    {
        const float p = ll1A1 + lh0A.y, q = hl0A.y + hh0A.y;
        r0A[2] = 0.5f * (p + q);  r0A[3] = 0.5f * (p - q);
        const float pm = ll1A1 - lh0A.y, qm = hl0A.y - hh0A.y;
        r1A[2] = 0.5f * (pm + qm); r1A[3] = 0.5f * (pm - qm);
    }
    {
        const float p = ll1B0 + lh0B.x, q = hl0B.x + hh0B.x;
        r0B[0] = 0.5f * (p + q);  r0B[1] = 0.5f * (p - q);
        const float pm = ll1B0 - lh0B.x, qm = hl0B.x - hh0B.x;
        r1B[0] = 0.5f * (pm + qm); r1B[1] = 0.5f * (pm - qm);
    }
    {
        const float p = ll1B1 + lh0B.y, q = hl0B.y + hh0B.y;
        r0B[2] = 0.5f * (p + q);  r0B[3] = 0.5f * (p - q);
        const float pm = ll1B1 - lh0B.y, qm = hl0B.y - hh0B.y;
        r1B[2] = 0.5f * (pm + qm); r1B[3] = 0.5f * (pm - qm);
    }

    // ---- stores: 4 NT float4, each fully contiguous across the wave ----
    float* __restrict__ ob =
        out + ((size_t)nc * 512 + (i0 << 1)) * 512 + (u << 2);
    __builtin_nontemporal_store(r0A, (f32x4*)(ob));
    __builtin_nontemporal_store(r0B, (f32x4*)(ob + 256));
    __builtin_nontemporal_store(r1A, (f32x4*)(ob + 512));
    __builtin_nontemporal_store(r1B, (f32x4*)(ob + 768));
}

extern "C" void kernel_launch(void* const* d_in, const int* in_sizes, int n_in,
                              void* d_out, int out_size, void* d_ws, size_t ws_size,
                              hipStream_t stream) {
    const float* h = (const float*)d_in[0];
    float* out = (float*)d_out;
    dim3 grid(64, 48);       // 64 blocks x 4 waves = 256 row-pairs; x (n*3+c)
    wave_decoder_kernel<<<grid, dim3(256, 1, 1), 0, stream>>>(h, out);
}